// Round 4
// baseline (56.212 us; speedup 1.0000x reference)
//
#include <hip/hip_runtime.h>
#include <math.h>

#define BB 64
#define HH 80
#define WW 3000
#define RAD 16
#define TW 96             // output columns per strip
#define NSTRIP 32         // ceil(3000/96)
#define NT 960
#define EPSF 1e-8f

// P[raw][c]: exclusive column prefix of (Sx,Sxx) f32x2; raw = 0..80.
// word = raw*SP + 16*(c>>3) + 2*(c&7)   (12 segs x 16 words + 4 pad)
#define SP 196
#define P_WORDS (81 * SP)            // 15876
#define SCR_OFF P_WORDS              // scratch[c][sub]: c*20 + 2*sub (96*20 = 1920)
#define ICH_OFF (SCR_OFF + 96 * 20)  // 17796
#define TOT_WORDS (ICH_OFF + 80)     // 17876 words = 71504 B -> 2 blocks/CU

typedef float f32x2 __attribute__((ext_vector_type(2)));
typedef float f32x4 __attribute__((ext_vector_type(4)));

// compile-time-folding element selectors (named registers only — no arrays)
#define E4(V, J) ((J) == 0 ? (V).x : ((J) == 1 ? (V).y : ((J) == 2 ? (V).z : (V).w)))
#define F40(Q) E4((Q) < 4 ? v0 : (Q) < 8 ? v1 : (Q) < 12 ? v2 : (Q) < 16 ? v3 : (Q) < 20 ? v4 : \
                  (Q) < 24 ? v5 : (Q) < 28 ? v6 : (Q) < 32 ? v7 : (Q) < 36 ? v8 : v9, (Q) & 3)

__global__ __launch_bounds__(NT, 8)
void localnorm_kernel(const float* __restrict__ in, float* __restrict__ out) {
    extern __shared__ float smemf[];

    const int t     = threadIdx.x;
    const int strip = blockIdx.x % NSTRIP;
    const int b     = blockIdx.x / NSTRIP;
    const int c0    = strip * TW;

    // phase 0: per-row vertical-count reciprocals
    if (t < HH) {
        int lo = max(t - RAD, 0), hi = min(t + RAD, HH - 1);
        smemf[ICH_OFF + t] = 1.0f / (float)(hi - lo + 1);
    }

    // ---- phase 2: load 40 f32 window from GLOBAL, horizontal 33-tap (Sx,Sxx), write H rows ----
    // 80 rows x 12 segs of 8 cols = 960 threads.
    {
        const int s   = t % 12;
        const int row = t / 12;
        const int gb  = c0 - 16 + 8 * s;       // first loaded col (global)
        const float* rp = in + (size_t)b * (HH * WW) + (size_t)row * WW;
        f32x4 v0, v1, v2, v3, v4, v5, v6, v7, v8, v9;
        if (gb >= 0 && gb + 40 <= WW) {
            v0 = *(const f32x4*)(rp + gb);
            v1 = *(const f32x4*)(rp + gb + 4);
            v2 = *(const f32x4*)(rp + gb + 8);
            v3 = *(const f32x4*)(rp + gb + 12);
            v4 = *(const f32x4*)(rp + gb + 16);
            v5 = *(const f32x4*)(rp + gb + 20);
            v6 = *(const f32x4*)(rp + gb + 24);
            v7 = *(const f32x4*)(rp + gb + 28);
            v8 = *(const f32x4*)(rp + gb + 32);
            v9 = *(const f32x4*)(rp + gb + 36);
        } else {
            #define LDG1(C) (((C) >= 0 && (C) < WW) ? rp[(C)] : 0.f)
            #define GV4(V, CB) { V.x = LDG1(CB); V.y = LDG1((CB)+1); V.z = LDG1((CB)+2); V.w = LDG1((CB)+3); }
            GV4(v0, gb)      GV4(v1, gb + 4)  GV4(v2, gb + 8)  GV4(v3, gb + 12)
            GV4(v4, gb + 16) GV4(v5, gb + 20) GV4(v6, gb + 24) GV4(v7, gb + 28)
            GV4(v8, gb + 32) GV4(v9, gb + 36)
        }
        // initial window: Q = 0..32 (cols 8s-16 .. 8s+16), 2-way ILP split
        float f32_ = F40(32);
        float axA = f32_, axB = 0.f;
        float qxA = f32_ * f32_, qxB = 0.f;
        #pragma unroll
        for (int q = 0; q < 32; q += 2) {
            float fa = F40(q), fb = F40(q + 1);
            axA += fa;                 axB += fb;
            qxA = fmaf(fa, fa, qxA);   qxB = fmaf(fb, fb, qxB);
        }
        float ax = axA + axB, axx = qxA + qxB;
        float* pw = smemf + (row + 1) * SP + 16 * s;   // H(row) lives at raw = row+1
        #pragma unroll
        for (int k = 0; k < 8; ++k) {
            f32x2 h; h.x = ax; h.y = axx;
            *(f32x2*)(pw + 2 * k) = h;
            if (k != 7) {
                float fs = F40(k), fe = F40(k + 33);
                ax += fe - fs;
                axx = fmaf(fe, fe, axx);
                axx = fmaf(-fs, fs, axx);
            }
        }
    }
    __syncthreads();

    // ---- scan A: per-column local inclusive scans of 8 H rows (kept in registers) ----
    // 96 cols x 10 subs = 960 threads.
    const int sc_c   = t % 96;
    const int sc_sub = t / 96;                          // 0..9
    const int cw     = 16 * (sc_c >> 3) + 2 * (sc_c & 7);
    f32x2 ss0, ss1, ss2, ss3, ss4, ss5, ss6, ss7;
    {
        const float* pr = smemf + (1 + 8 * sc_sub) * SP + cw;
        f32x2 h0 = *(const f32x2*)(pr);
        f32x2 h1 = *(const f32x2*)(pr + SP);
        f32x2 h2 = *(const f32x2*)(pr + 2 * SP);
        f32x2 h3 = *(const f32x2*)(pr + 3 * SP);
        f32x2 h4 = *(const f32x2*)(pr + 4 * SP);
        f32x2 h5 = *(const f32x2*)(pr + 5 * SP);
        f32x2 h6 = *(const f32x2*)(pr + 6 * SP);
        f32x2 h7 = *(const f32x2*)(pr + 7 * SP);
        ss0 = h0;        ss1 = ss0 + h1;  ss2 = ss1 + h2;  ss3 = ss2 + h3;
        ss4 = ss3 + h4;  ss5 = ss4 + h5;  ss6 = ss5 + h6;  ss7 = ss6 + h7;
        *(f32x2*)(smemf + SCR_OFF + sc_c * 20 + 2 * sc_sub) = ss7;
    }
    __syncthreads();

    // ---- scan B: exclusive scan of the 10 per-column partials (96 threads) ----
    if (t < 96) {
        float* sc = smemf + SCR_OFF + t * 20;
        f32x4 q0 = *(const f32x4*)(sc);
        f32x4 q1 = *(const f32x4*)(sc + 4);
        f32x4 q2 = *(const f32x4*)(sc + 8);
        f32x4 q3 = *(const f32x4*)(sc + 12);
        f32x4 q4 = *(const f32x4*)(sc + 16);
        f32x2 o0; o0.x = 0.f; o0.y = 0.f;
        f32x2 o1 = q0.xy;
        f32x2 o2 = o1 + q0.zw;
        f32x2 o3 = o2 + q1.xy;
        f32x2 o4 = o3 + q1.zw;
        f32x2 o5 = o4 + q2.xy;
        f32x2 o6 = o5 + q2.zw;
        f32x2 o7 = o6 + q3.xy;
        f32x2 o8 = o7 + q3.zw;
        f32x2 o9 = o8 + q4.xy;
        *(f32x2*)(sc)      = o0;  *(f32x2*)(sc + 2)  = o1;
        *(f32x2*)(sc + 4)  = o2;  *(f32x2*)(sc + 6)  = o3;
        *(f32x2*)(sc + 8)  = o4;  *(f32x2*)(sc + 10) = o5;
        *(f32x2*)(sc + 12) = o6;  *(f32x2*)(sc + 14) = o7;
        *(f32x2*)(sc + 16) = o8;  *(f32x2*)(sc + 18) = o9;
    }
    __syncthreads();

    // ---- scan C: add column offsets, write exclusive prefix P (overwrites H slots) ----
    {
        f32x2 off = *(const f32x2*)(smemf + SCR_OFF + sc_c * 20 + 2 * sc_sub);
        float* pw = smemf + (1 + 8 * sc_sub) * SP + cw;
        *(f32x2*)(pw)          = ss0 + off;
        *(f32x2*)(pw + SP)     = ss1 + off;
        *(f32x2*)(pw + 2 * SP) = ss2 + off;
        *(f32x2*)(pw + 3 * SP) = ss3 + off;
        *(f32x2*)(pw + 4 * SP) = ss4 + off;
        *(f32x2*)(pw + 5 * SP) = ss5 + off;
        *(f32x2*)(pw + 6 * SP) = ss6 + off;
        *(f32x2*)(pw + 7 * SP) = ss7 + off;
        if (sc_sub == 0) {
            f32x2 z; z.x = 0.f; z.y = 0.f;
            *(f32x2*)(smemf + cw) = z;       // P[0][c] = 0
        }
    }
    __syncthreads();

    // ---- phase 3: V-window = P[rhi]-P[rlo]; normalize with x reloaded from global (L2-hot) ----
    // 96 cols x 10 bands of 8 rows = 960 threads.
    {
        const int c    = sc_c;
        const int band = sc_sub;
        const int r0   = band * 8;
        const int gc   = c0 + c;
        if (gc < WW) {
            const float icw = 1.0f / (float)(min(gc + RAD, WW - 1) - max(gc - RAD, 0) + 1);
            f32x4 f4a = *(const f32x4*)(smemf + ICH_OFF + r0);
            f32x4 f4b = *(const f32x4*)(smemf + ICH_OFF + r0 + 4);
            const float* xin  = in  + (size_t)b * (HH * WW) + gc;
            float*       xout = out + (size_t)b * (HH * WW) + gc;
            #pragma unroll
            for (int k = 0; k < 8; ++k) {
                const int r   = r0 + k;
                const int rhi = min(r + 17, 80);
                const int rlo = max(r - 16, 0);
                f32x2 Ph = *(const f32x2*)(smemf + rhi * SP + cw);
                f32x2 Pl = *(const f32x2*)(smemf + rlo * SP + cw);
                f32x2 V  = Ph - Pl;
                const float ninv = E4(k < 4 ? f4a : f4b, k & 3) * icw;
                float mean = V.x * ninv;
                float exx  = V.y * ninv;
                float var  = fmaxf(exx - mean * mean, 0.f);
                float sd   = __builtin_amdgcn_sqrtf(var);
                float x    = xin[(size_t)r * WW];
                xout[(size_t)r * WW] = (x - mean) * __builtin_amdgcn_rcpf(sd + EPSF);
            }
        }
    }
}

extern "C" void kernel_launch(void* const* d_in, const int* in_sizes, int n_in,
                              void* d_out, int out_size, void* d_ws, size_t ws_size,
                              hipStream_t stream) {
    const float* in = (const float*)d_in[0];
    float* out = (float*)d_out;

    const size_t lds_bytes = (size_t)TOT_WORDS * sizeof(float);  // 71504
    static bool attr_set = false;
    if (!attr_set) {
        (void)hipFuncSetAttribute((const void*)localnorm_kernel,
                                  hipFuncAttributeMaxDynamicSharedMemorySize,
                                  (int)lds_bytes);
        attr_set = true;
    }

    dim3 grid(BB * NSTRIP);
    dim3 block(NT);
    localnorm_kernel<<<grid, block, lds_bytes, stream>>>(in, out);
}

// Round 5
// 39.134 us; speedup vs baseline: 1.4364x; 1.4364x over previous
//
#include <hip/hip_runtime.h>
#include <hip/hip_bf16.h>
#include <math.h>

#define BB 64
#define HH 80
#define WW 3000
#define RAD 16
#define TW 96             // output columns per strip
#define NLOAD 128         // loaded columns = TW + 2*16 halo
#define XSW 68            // Xs words/row: 64 data + 4 pad (68 % 32 == 4 -> b128 bank-spread)
#define HXS 116           // Hxp col stride: 112 raw rows + 4 pad (116 % 32 == 20 -> b128 bank-spread)
#define NSTRIP 32         // ceil(3000/96)
#define NT 1024
#define EPSF 1e-8f

#define XS_WORDS (HH * XSW)             // 5440
#define HXP_OFF  XS_WORDS
#define HXP_WORDS (TW * HXS)            // 11136
#define ICH_OFF  (XS_WORDS + HXP_WORDS) // 16576
#define TOT_WORDS (ICH_OFF + HH)        // 16656 words = 66624 B -> 2 blocks/CU

typedef float f32x2 __attribute__((ext_vector_type(2)));

__device__ __forceinline__ float bflo(uint32_t w) { return __uint_as_float(w << 16); }
__device__ __forceinline__ float bfhi(uint32_t w) { return __uint_as_float(w & 0xffff0000u); }
__device__ __forceinline__ uint32_t packbf2(float lo, float hi) {
    union { __hip_bfloat162 h2; uint32_t u; } u;
    u.h2 = __hip_bfloat162(__float2bfloat16(lo), __float2bfloat16(hi));
    return u.u;
}
// unpack a bf16-packed word into f32x2 {lo, hi} (2 VALU ops); pk_add accumulates both halves
__device__ __forceinline__ f32x2 uw(uint32_t w) {
    f32x2 r; r.x = bflo(w); r.y = bfhi(w); return r;
}

// compile-time-folding element selectors (named registers only — no arrays/unions)
#define E4(V, J) ((J) == 0 ? (V).x : ((J) == 1 ? (V).y : ((J) == 2 ? (V).z : (V).w)))
#define W20(Q) E4((Q) < 4 ? v0 : (Q) < 8 ? v1 : (Q) < 12 ? v2 : (Q) < 16 ? v3 : v4, (Q) & 3)
#define G48(Q) E4((Q) < 4 ? R0 : (Q) < 8 ? R1 : (Q) < 12 ? R2 : (Q) < 16 ? R3 : (Q) < 20 ? R4 : \
                  (Q) < 24 ? R5 : (Q) < 28 ? R6 : (Q) < 32 ? R7 : (Q) < 36 ? R8 : \
                  (Q) < 40 ? R9 : (Q) < 44 ? R10 : R11, (Q) & 3)

__global__ __launch_bounds__(NT, 8)
void localnorm_kernel(const float* __restrict__ in, float* __restrict__ out) {
    extern __shared__ uint32_t smem[];
    uint32_t* Hxp = smem + HXP_OFF;          // Hxp[col][raw_r] at col*HXS + raw_r; raw_r = logical+16
    float* inv_ch = (float*)(smem + ICH_OFF);

    const int t     = threadIdx.x;
    const int strip = blockIdx.x % NSTRIP;
    const int b     = blockIdx.x / NSTRIP;
    const int c0    = strip * TW;

    // phase 0: per-row reciprocals + zero Hxp pad rows (raw 0..15 and 96..111) for all 96 cols
    if (t < HH) {
        int lo = max(t - RAD, 0), hi = min(t + RAD, HH - 1);
        inv_ch[t] = 1.0f / (float)(hi - lo + 1);
    }
    if (t < 768) {
        const int col = t >> 3;
        const int c8  = t & 7;
        const int off = col * HXS + ((c8 < 4) ? (c8 * 4) : (96 + (c8 - 4) * 4));
        *(uint4*)(Hxp + off) = make_uint4(0u, 0u, 0u, 0u);
    }

    // phase 1: load 128 cols x 80 rows, pack to bf16 pairs. 80 rows x 32 quads = 2560 tasks.
    {
        const float* inb = in + (size_t)b * (HH * WW);
        #pragma unroll
        for (int it = 0; it < 3; ++it) {
            const int id = t + it * NT;
            if (it < 2 || id < 2560) {
                const int row = id >> 5;
                const int q   = id & 31;
                const int gc  = c0 - 16 + 4 * q;
                uint2 w2;
                if (gc >= 0 && gc + 4 <= WW) {
                    float4 v = *(const float4*)(inb + (size_t)row * WW + gc);
                    w2.x = packbf2(v.x, v.y);
                    w2.y = packbf2(v.z, v.w);
                } else {
                    float p0 = (gc     >= 0 && gc     < WW) ? inb[(size_t)row * WW + gc]     : 0.f;
                    float p1 = (gc + 1 >= 0 && gc + 1 < WW) ? inb[(size_t)row * WW + gc + 1] : 0.f;
                    float p2 = (gc + 2 >= 0 && gc + 2 < WW) ? inb[(size_t)row * WW + gc + 2] : 0.f;
                    float p3 = (gc + 3 >= 0 && gc + 3 < WW) ? inb[(size_t)row * WW + gc + 3] : 0.f;
                    w2.x = packbf2(p0, p1);
                    w2.y = packbf2(p2, p3);
                }
                *(uint2*)(smem + row * XSW + 2 * q) = w2;
            }
        }
    }
    __syncthreads();

    // phase 2: fused horizontal 33-tap sums of x AND x^2; bf16-packed (Sx,Sxx) word per col.
    // 80 rows x 12 segs of 8 cols = 960 threads; 5 b128 reads each. Init via pk_add/pk_fma.
    {
        const int row = t % HH;
        const int seg = t / HH;
        if (seg < 12) {
            const uint32_t* xr = smem + row * XSW + seg * 4;
            uint4 v0 = *(const uint4*)(xr);
            uint4 v1 = *(const uint4*)(xr + 4);
            uint4 v2 = *(const uint4*)(xr + 8);
            uint4 v3 = *(const uint4*)(xr + 12);
            uint4 v4 = *(const uint4*)(xr + 16);
            // initial window e0..e32: packed pair accumulate (4 ops/word), 2-way ILP split
            float l16 = bflo(W20(16));
            f32x2 pA; pA.x = l16;       pA.y = 0.f;
            f32x2 qA; qA.x = l16 * l16; qA.y = 0.f;
            f32x2 pB; pB.x = 0.f; pB.y = 0.f;
            f32x2 qB; qB.x = 0.f; qB.y = 0.f;
            #pragma unroll
            for (int q = 0; q < 16; q += 2) {
                f32x2 uA = uw(W20(q));
                f32x2 uB = uw(W20(q + 1));
                pA += uA;      pB += uB;
                qA += uA * uA; qB += uB * uB;
            }
            f32x2 ps = pA + pB, qs = qA + qB;
            float ax  = ps.x + ps.y;
            float axx = qs.x + qs.y;
            uint32_t* hw = Hxp + (seg * 8) * HXS + row + 16;
            #pragma unroll
            for (int k = 0; k < 4; ++k) {
                uint32_t wS = W20(k), wE = W20(k + 16);
                float lS = bflo(wS), hE = bfhi(wE);
                float a1x  = ax - lS + hE;
                float a1xx = axx - lS * lS + hE * hE;
                hw[(2 * k) * HXS]     = packbf2(ax, axx);
                hw[(2 * k + 1) * HXS] = packbf2(a1x, a1xx);
                if (k != 3) {
                    float hS = bfhi(wS), lN = bflo(W20(k + 17));
                    ax  = a1x - hS + lN;
                    axx = a1xx - hS * hS + lN * lN;
                }
            }
        }
    }
    __syncthreads();

    // phase 3: vertical 33-tap sums of (Sx,Sxx) via pk_add, bands of 16 rows to amortize init.
    // 96 cols x 5 bands = 480 threads; 12 contiguous b128 reads (words r0..r0+47).
    {
        const int c    = t % TW;
        const int band = t / TW;
        const int gc   = c0 + c;
        if (band < 5 && gc < WW) {
            const int r0 = band * 16;
            const uint32_t* hp = Hxp + c * HXS + r0;   // raw rows r0 .. r0+47
            uint4 R0  = *(const uint4*)(hp);
            uint4 R1  = *(const uint4*)(hp + 4);
            uint4 R2  = *(const uint4*)(hp + 8);
            uint4 R3  = *(const uint4*)(hp + 12);
            uint4 R4  = *(const uint4*)(hp + 16);
            uint4 R5  = *(const uint4*)(hp + 20);
            uint4 R6  = *(const uint4*)(hp + 24);
            uint4 R7  = *(const uint4*)(hp + 28);
            uint4 R8  = *(const uint4*)(hp + 32);
            uint4 R9  = *(const uint4*)(hp + 36);
            uint4 R10 = *(const uint4*)(hp + 40);
            uint4 R11 = *(const uint4*)(hp + 44);
            // init acc = sum of raws r0..r0+32 (words 0..32), 3 ops/word, 2-way split
            f32x2 aA = uw(G48(32));
            f32x2 aB; aB.x = 0.f; aB.y = 0.f;
            #pragma unroll
            for (int q = 0; q < 32; q += 2) {
                aA += uw(G48(q));
                aB += uw(G48(q + 1));
            }
            f32x2 acc = aA + aB;                       // {Sx_v, Sxx_v}
            const float icw = 1.0f / (float)(min(gc + RAD, WW - 1) - max(gc - RAD, 0) + 1);
            const int  xwoff  = (c + 16) >> 1;
            const bool hiHalf = ((c + 16) & 1) != 0;
            float* outb = out + (size_t)b * (HH * WW);
            #pragma unroll
            for (int k = 0; k < 16; ++k) {
                const int r = r0 + k;
                const float ninv = inv_ch[r] * icw;
                float mean = acc.x * ninv;
                float exx  = acc.y * ninv;
                float var  = fmaxf(exx - mean * mean, 0.f);
                float sd   = __builtin_amdgcn_sqrtf(var);
                uint32_t xw = smem[r * XSW + xwoff];
                float xv = hiHalf ? bfhi(xw) : bflo(xw);
                outb[(size_t)r * WW + gc] = (xv - mean) * __builtin_amdgcn_rcpf(sd + EPSF);
                if (k != 15) {
                    acc += uw(G48(k + 33)) - uw(G48(k));   // 2x v_pk_add_f32
                }
            }
        }
    }
}

extern "C" void kernel_launch(void* const* d_in, const int* in_sizes, int n_in,
                              void* d_out, int out_size, void* d_ws, size_t ws_size,
                              hipStream_t stream) {
    const float* in = (const float*)d_in[0];
    float* out = (float*)d_out;

    const size_t lds_bytes = (size_t)TOT_WORDS * sizeof(uint32_t);  // 66624
    static bool attr_set = false;
    if (!attr_set) {
        (void)hipFuncSetAttribute((const void*)localnorm_kernel,
                                  hipFuncAttributeMaxDynamicSharedMemorySize,
                                  (int)lds_bytes);
        attr_set = true;
    }

    dim3 grid(BB * NSTRIP);
    dim3 block(NT);
    localnorm_kernel<<<grid, block, lds_bytes, stream>>>(in, out);
}